// Round 3
// baseline (426.782 us; speedup 1.0000x reference)
//
#include <hip/hip_runtime.h>
#include <hip/hip_bf16.h>

#define BB 4
#define NN 4096
#define FF 128
#define UU 64
#define LOG2E 1.4426950408889634f

typedef float  f32x4   __attribute__((ext_vector_type(4)));
typedef __bf16 bf16x8  __attribute__((ext_vector_type(8)));
typedef int    int4v   __attribute__((ext_vector_type(4)));
typedef float  flt4v   __attribute__((ext_vector_type(4)));
typedef unsigned short us4 __attribute__((ext_vector_type(4)));

__device__ __forceinline__ unsigned short f2bf(float x) {
    unsigned u = __float_as_uint(x);
    u += 0x7FFFu + ((u >> 16) & 1u);   // round-to-nearest-even
    return (unsigned short)(u >> 16);
}

__device__ __forceinline__ float fexp2(float x) {
#if defined(__has_builtin)
# if __has_builtin(__builtin_amdgcn_exp2f)
    return __builtin_amdgcn_exp2f(x);
# else
    return exp2f(x);
# endif
#else
    return exp2f(x);
#endif
}

// Kernel 1: Wh = h @ W (fp32), src/dst = (Wh·a)/ln2, WhT bf16 [b][u][j]
__global__ __launch_bounds__(256) void prep_kernel(
    const float* __restrict__ h, const float* __restrict__ W,
    const float* __restrict__ a,
    unsigned short* __restrict__ WhT, float* __restrict__ src, float* __restrict__ dst)
{
    __shared__ float Wl[FF][UU];             // 32 KB
    __shared__ unsigned short tile[16][UU];  // 2 KB
    const int t = threadIdx.x, w = t >> 6, l = t & 63;
    const int bid = blockIdx.x;
    const int b = bid >> 8;                  // N/16 = 256 blocks per batch
    const int i0 = (bid & 255) << 4;

    // stage W into LDS (8192 floats, 32 per thread)
    {
        const flt4v* Wv = (const flt4v*)W;
        flt4v* Wlv = (flt4v*)&Wl[0][0];
        #pragma unroll
        for (int k = 0; k < 8; ++k) Wlv[t + 256 * k] = Wv[t + 256 * k];
    }
    __syncthreads();

    // wave w computes rows i0 + 4w .. i0 + 4w+3 ; lane = u
    float acc[4] = {0.f, 0.f, 0.f, 0.f};
    const float* hrow = h + ((size_t)(b * NN + i0 + w * 4) * FF);
    #pragma unroll 8
    for (int fc = 0; fc < 32; ++fc) {
        const int f0 = fc << 2;
        flt4v h0 = *(const flt4v*)(hrow + f0);
        flt4v h1 = *(const flt4v*)(hrow + FF + f0);
        flt4v h2 = *(const flt4v*)(hrow + 2 * FF + f0);
        flt4v h3 = *(const flt4v*)(hrow + 3 * FF + f0);
        #pragma unroll
        for (int e = 0; e < 4; ++e) {
            float wv = Wl[f0 + e][l];
            acc[0] += h0[e] * wv;
            acc[1] += h1[e] * wv;
            acc[2] += h2[e] * wv;
            acc[3] += h3[e] * wv;
        }
    }

    float a1 = a[l], a2 = a[UU + l];
    #pragma unroll
    for (int k = 0; k < 4; ++k) {
        float s = acc[k] * a1, d = acc[k] * a2;
        #pragma unroll
        for (int off = 32; off > 0; off >>= 1) {
            s += __shfl_xor(s, off, 64);
            d += __shfl_xor(d, off, 64);
        }
        int i = i0 + w * 4 + k;
        if (l == 0) {
            src[b * NN + i] = s * LOG2E;   // fold 1/ln2 -> exp2 downstream
            dst[b * NN + i] = d * LOG2E;
        }
        tile[w * 4 + k][l] = f2bf(acc[k]);
    }
    __syncthreads();

    // transposed store: thread t -> u = t>>2, 4 consecutive i
    {
        int u = t >> 2, ic = (t & 3) << 2;
        us4 vv = { tile[ic + 0][u], tile[ic + 1][u], tile[ic + 2][u], tile[ic + 3][u] };
        *(us4*)(WhT + ((size_t)(b * UU + u) * NN) + i0 + ic) = vv;
    }
}

#define MFMA16(A, B, C) __builtin_amdgcn_mfma_f32_16x16x32_bf16(A, B, C, 0, 0, 0)

// Kernel 2: flash-style rank-1-score attention + BN + ReLU
// 4 waves share 16 rows, stripe j (64 j / wave / iter). adj (HBM) prefetched
// 2 tiles deep; loaded int4v's packed to 8-bit masks on arrival to cap VGPRs.
__global__ __launch_bounds__(256, 4) void gat_kernel(
    const int* __restrict__ adj, const unsigned short* __restrict__ WhT,
    const float* __restrict__ src, const float* __restrict__ dst,
    const float* __restrict__ gamma, const float* __restrict__ beta,
    const float* __restrict__ mmean, const float* __restrict__ mvar,
    float* __restrict__ out)
{
    __shared__ float opart[4][16][UU];  // 16 KB
    __shared__ float lpart[4][16];
    const int t = threadIdx.x, w = t >> 6, l = t & 63;
    const int bid = blockIdx.x;
    const int b = bid >> 8;
    const int i0 = (bid & 255) << 4;
    const int row = l & 15;     // A-frag row (i within tile) == B-frag col (u low)
    const int kg = l >> 4;      // k-group 0..3
    const int ko = kg << 3;
    const int i = i0 + row;

    const float srow = src[b * NN + i];
    const int* adjr = adj + ((size_t)(b * NN + i) << 12);
    const float* dstb = dst + b * NN;
    const unsigned short* w0 = WhT + ((size_t)(b * UU + row) * NN);

    f32x4 acc0 = {0,0,0,0}, acc1 = {0,0,0,0}, acc2 = {0,0,0,0}, acc3 = {0,0,0,0};
    float ls0 = 0.f, ls1 = 0.f;

    // in-flight adj registers (two tiles deep)
    int4v Pa, Pb, Pc, Pd, Qa, Qb, Qc, Qd;

    #define LDADJ(va, vb, vc, vd, bs)                       \
    {                                                       \
        va = *(const int4v*)(adjr + (bs) + ko);             \
        vb = *(const int4v*)(adjr + (bs) + ko + 4);         \
        vc = *(const int4v*)(adjr + (bs) + ko + 32);        \
        vd = *(const int4v*)(adjr + (bs) + ko + 36);        \
    }
    // adj values are exactly 0/1 -> OR-pack 8 of them into a byte mask
    #define PACK(va, vb, vc, vd, m0, m1)                                 \
    {                                                                    \
        m0 = (unsigned)(va[0] | (va[1] << 1) | (va[2] << 2) | (va[3] << 3) \
           | (vb[0] << 4) | (vb[1] << 5) | (vb[2] << 6) | (vb[3] << 7)); \
        m1 = (unsigned)(vc[0] | (vc[1] << 1) | (vc[2] << 2) | (vc[3] << 3) \
           | (vd[0] << 4) | (vd[1] << 5) | (vd[2] << 6) | (vd[3] << 7)); \
    }

    // softmax numerator for one j -> bf16 A-fragment element
    #define PE(af, e, Dv, ei, m, ls)                                \
    {                                                               \
        float tt = srow + Dv[ei];                                   \
        tt = fmaxf(tt, 0.2f * tt);      /* LeakyReLU (log2 units) */\
        float pp = fexp2(tt);                                       \
        pp = (m & (1u << e)) ? pp : 0.0f;                           \
        ls += pp;                                                   \
        af[e] = (__bf16)pp;                                         \
    }

    auto body = [&](int bs, unsigned m0, unsigned m1) {
        // --- k-half 0: j = bs+ko .. bs+ko+7 ---
        const flt4v  D0a = *(const flt4v*)(dstb + bs + ko);
        const flt4v  D0b = *(const flt4v*)(dstb + bs + ko + 4);
        const bf16x8 B00 = *(const bf16x8*)(w0 + bs + ko);
        const bf16x8 B01 = *(const bf16x8*)(w0 + 16 * NN + bs + ko);
        const bf16x8 B02 = *(const bf16x8*)(w0 + 32 * NN + bs + ko);
        const bf16x8 B03 = *(const bf16x8*)(w0 + 48 * NN + bs + ko);
        bf16x8 af0;
        PE(af0, 0, D0a, 0, m0, ls0) PE(af0, 1, D0a, 1, m0, ls0)
        PE(af0, 2, D0a, 2, m0, ls0) PE(af0, 3, D0a, 3, m0, ls0)
        PE(af0, 4, D0b, 0, m0, ls0) PE(af0, 5, D0b, 1, m0, ls0)
        PE(af0, 6, D0b, 2, m0, ls0) PE(af0, 7, D0b, 3, m0, ls0)
        acc0 = MFMA16(af0, B00, acc0);
        acc1 = MFMA16(af0, B01, acc1);
        acc2 = MFMA16(af0, B02, acc2);
        acc3 = MFMA16(af0, B03, acc3);
        // --- k-half 1: j = bs+32+ko .. ---
        const flt4v  D1a = *(const flt4v*)(dstb + bs + ko + 32);
        const flt4v  D1b = *(const flt4v*)(dstb + bs + ko + 36);
        const bf16x8 B10 = *(const bf16x8*)(w0 + bs + ko + 32);
        const bf16x8 B11 = *(const bf16x8*)(w0 + 16 * NN + bs + ko + 32);
        const bf16x8 B12 = *(const bf16x8*)(w0 + 32 * NN + bs + ko + 32);
        const bf16x8 B13 = *(const bf16x8*)(w0 + 48 * NN + bs + ko + 32);
        bf16x8 af1;
        PE(af1, 0, D1a, 0, m1, ls1) PE(af1, 1, D1a, 1, m1, ls1)
        PE(af1, 2, D1a, 2, m1, ls1) PE(af1, 3, D1a, 3, m1, ls1)
        PE(af1, 4, D1b, 0, m1, ls1) PE(af1, 5, D1b, 1, m1, ls1)
        PE(af1, 6, D1b, 2, m1, ls1) PE(af1, 7, D1b, 3, m1, ls1)
        acc0 = MFMA16(af1, B10, acc0);
        acc1 = MFMA16(af1, B11, acc1);
        acc2 = MFMA16(af1, B12, acc2);
        acc3 = MFMA16(af1, B13, acc3);
    };

    // wave w owns j-chunks {w, w+4, w+8, ...} of 64 columns (16 tiles)
    int bs = w << 6;
    LDADJ(Pa, Pb, Pc, Pd, bs)          // tile it=0
    LDADJ(Qa, Qb, Qc, Qd, bs + 256)    // tile it=1

    for (int it = 0; it < 16; it += 2) {
        unsigned m0, m1;
        PACK(Pa, Pb, Pc, Pd, m0, m1)                 // waits on P arrival
        if (it < 14) LDADJ(Pa, Pb, Pc, Pd, bs + 512) // prefetch tile it+2
        body(bs, m0, m1);
        PACK(Qa, Qb, Qc, Qd, m0, m1)
        if (it < 13) LDADJ(Qa, Qb, Qc, Qd, bs + 768) // prefetch tile it+3
        body(bs + 256, m0, m1);
        bs += 512;
    }
    #undef PE
    #undef LDADJ
    #undef PACK

    // row-sum partials: lanes {r, r+16, r+32, r+48} hold row r
    float lsum = ls0 + ls1;
    lsum += __shfl_xor(lsum, 16, 64);
    lsum += __shfl_xor(lsum, 32, 64);
    if (l < 16) lpart[w][l] = lsum;

    // C layout: col = l&15 (u low), row(m) = kg*4 + reg
    #pragma unroll
    for (int r = 0; r < 4; ++r) {
        opart[w][kg * 4 + r][      row] = acc0[r];
        opart[w][kg * 4 + r][16 + row] = acc1[r];
        opart[w][kg * 4 + r][32 + row] = acc2[r];
        opart[w][kg * 4 + r][48 + row] = acc3[r];
    }
    __syncthreads();

    // combine 4 wave-partials, normalize, BN + ReLU, coalesced store
    const int u = t & 63;
    const float inv = rsqrtf(mvar[u] + 1e-3f);
    const float sc = gamma[u] * inv;
    const float bi = beta[u] - mmean[u] * sc;
    const int ib = (t >> 6) << 2;
    #pragma unroll
    for (int r = 0; r < 4; ++r) {
        int il = ib + r;
        float ltot = lpart[0][il] + lpart[1][il] + lpart[2][il] + lpart[3][il];
        float v = opart[0][il][u] + opart[1][il][u] + opart[2][il][u] + opart[3][il][u];
        v = v / ltot * sc + bi;
        out[((size_t)(b * NN + i0 + il) << 6) + u] = fmaxf(v, 0.f);
    }
}

extern "C" void kernel_launch(void* const* d_in, const int* in_sizes, int n_in,
                              void* d_out, int out_size, void* d_ws, size_t ws_size,
                              hipStream_t stream) {
    const float* h     = (const float*)d_in[0];
    const int*   adj   = (const int*)  d_in[1];
    const float* W     = (const float*)d_in[2];
    const float* a     = (const float*)d_in[3];
    const float* gamma = (const float*)d_in[4];
    const float* beta  = (const float*)d_in[5];
    const float* mmean = (const float*)d_in[6];
    const float* mvar  = (const float*)d_in[7];
    float* out = (float*)d_out;

    unsigned short* WhT = (unsigned short*)d_ws;                       // 2 MiB
    float* src = (float*)((char*)d_ws + (size_t)2 * 1024 * 1024);      // 64 KB
    float* dst = src + BB * NN;                                        // 64 KB

    prep_kernel<<<BB * (NN / 16), 256, 0, stream>>>(h, W, a, WhT, src, dst);
    gat_kernel<<<BB * (NN / 16), 256, 0, stream>>>(adj, WhT, src, dst,
                                                   gamma, beta, mmean, mvar, out);
}